// Round 5
// baseline (346.440 us; speedup 1.0000x reference)
//
#include <hip/hip_runtime.h>
#include <stdint.h>

typedef __bf16 bf16;
typedef __bf16 bf16x4 __attribute__((ext_vector_type(4)));
typedef __bf16 bf16x8 __attribute__((ext_vector_type(8)));
typedef float f32x4 __attribute__((ext_vector_type(4)));

#define AS1 __attribute__((address_space(1)))
#define AS3 __attribute__((address_space(3)))

__device__ __forceinline__ void async16(void* lds, const void* g) {
    __builtin_amdgcn_global_load_lds((AS1 void*)g, (AS3 void*)lds, 16, 0, 0);
}

// ---------------------------------------------------------------------------
// Prep: z<3 -> fp32->bf16 convert of X tensors; z==3 -> 4 weight transposes.
// ---------------------------------------------------------------------------
__global__ __launch_bounds__(256) void prep(
    const float* __restrict__ x0, const float* __restrict__ x1,
    const float* __restrict__ x2,
    bf16* __restrict__ y0, bf16* __restrict__ y1, bf16* __restrict__ y2,
    const float* __restrict__ s0, const float* __restrict__ s1,
    const float* __restrict__ s2, const float* __restrict__ s3,
    bf16* __restrict__ d0, bf16* __restrict__ d1,
    bf16* __restrict__ d2, bf16* __restrict__ d3) {
    const int z = blockIdx.z;
    const int t = threadIdx.x;
    if (z < 3) {
        const float* x = z == 0 ? x0 : z == 1 ? x1 : x2;
        bf16* y = z == 0 ? y0 : z == 1 ? y1 : y2;
        int i = (blockIdx.x * 256 + t) * 8;
        f32x4 a = *(const f32x4*)(x + i);
        f32x4 b = *(const f32x4*)(x + i + 4);
        bf16x8 o;
#pragma unroll
        for (int j = 0; j < 4; ++j) { o[j] = (bf16)a[j]; o[4 + j] = (bf16)b[j]; }
        *(bf16x8*)(y + i) = o;
        return;
    }
    // transpose: 1024 blocks handle 4 weights x 256 64x64 tiles
    const int bx = blockIdx.x;
    if (bx >= 1024) return;
    const int wsel = bx >> 8, tile = bx & 255;
    const float* W = wsel == 0 ? s0 : wsel == 1 ? s1 : wsel == 2 ? s2 : s3;
    bf16* Wt = wsel == 0 ? d0 : wsel == 1 ? d1 : wsel == 2 ? d2 : d3;
    const int k0 = (tile >> 4) * 64, n0 = (tile & 15) * 64;
    __shared__ float Ts[64 * 65];
    const int c = t & 63, r0 = t >> 6;
#pragma unroll
    for (int i = 0; i < 16; ++i) {
        int r = r0 + i * 4;
        Ts[r * 65 + c] = W[(size_t)(k0 + r) * 1024 + n0 + c];
    }
    __syncthreads();
#pragma unroll
    for (int i = 0; i < 16; ++i) {
        int r = r0 + i * 4;
        Wt[(size_t)(n0 + r) * 1024 + k0 + c] = (bf16)Ts[c * 65 + r];
    }
}

// ---------------------------------------------------------------------------
// 128x128 GEMM body, BK=64, xor-swizzled LDS rows (conflict-free b128 reads).
// C[M][N] = A[M][K]*Bt[N][K]^T * scale. 16 K-iterations at K=1024.
// ---------------------------------------------------------------------------
template <typename OutT>
__device__ __forceinline__ void gemm_body(const bf16* __restrict__ A,
                                          const bf16* __restrict__ Bt,
                                          OutT* __restrict__ C,
                                          int N, int K, float scale,
                                          int m0, int n0,
                                          bf16* As, bf16* Bs) {
    const int t = threadIdx.x;
    const int lane = t & 63;
    const int w = t >> 6;
    const int l15 = lane & 15;
    const int quad = lane >> 4;
    const int wm = w >> 1, wn = w & 1;

    f32x4 acc[4][4];
#pragma unroll
    for (int i = 0; i < 4; ++i)
#pragma unroll
        for (int j = 0; j < 4; ++j) acc[i][j] = (f32x4){0.f, 0.f, 0.f, 0.f};

    const bf16* gA[4];
    const bf16* gB[4];
#pragma unroll
    for (int j = 0; j < 4; ++j) {
        int c = j * 256 + t;
        int row = c >> 3, g = (c & 7) ^ (row & 7);
        gA[j] = A + (size_t)(m0 + row) * K + g * 8;
        gB[j] = Bt + (size_t)(n0 + row) * K + g * 8;
    }

    for (int k0 = 0; k0 < K; k0 += 64) {
        __syncthreads();
#pragma unroll
        for (int j = 0; j < 4; ++j) {
            async16(As + (j * 256 + w * 64) * 8, gA[j] + k0);
            async16(Bs + (j * 256 + w * 64) * 8, gB[j] + k0);
        }
        __syncthreads();
#pragma unroll
        for (int kk = 0; kk < 2; ++kk) {
            bf16x8 af[4], bfv[4];
#pragma unroll
            for (int mi = 0; mi < 4; ++mi) {
                int r = wm * 64 + mi * 16 + l15;
                af[mi] = *(const bf16x8*)&As[r * 64 + (((kk * 4 + quad) ^ (r & 7)) * 8)];
            }
#pragma unroll
            for (int ni = 0; ni < 4; ++ni) {
                int r = wn * 64 + ni * 16 + l15;
                bfv[ni] = *(const bf16x8*)&Bs[r * 64 + (((kk * 4 + quad) ^ (r & 7)) * 8)];
            }
#pragma unroll
            for (int mi = 0; mi < 4; ++mi)
#pragma unroll
                for (int ni = 0; ni < 4; ++ni)
                    acc[mi][ni] = __builtin_amdgcn_mfma_f32_16x16x32_bf16(
                        af[mi], bfv[ni], acc[mi][ni], 0, 0, 0);
        }
    }

#pragma unroll
    for (int mi = 0; mi < 4; ++mi)
#pragma unroll
        for (int ni = 0; ni < 4; ++ni)
#pragma unroll
            for (int r = 0; r < 4; ++r) {
                int row = m0 + wm * 64 + mi * 16 + quad * 4 + r;
                int col = n0 + wn * 64 + ni * 16 + l15;
                C[(size_t)row * N + col] = (OutT)(acc[mi][ni][r] * scale);
            }
}

// Batched Q/K/V projection. z=0: Qb=Xq*Wq^T*(0.125*log2e) -> S in log2 domain;
// z=1: Kb; z=2: VtG=(Xv*Wv)^T.
__global__ __launch_bounds__(256) void gemm_qkv(
    const bf16* __restrict__ Xq, const bf16* __restrict__ Xk, const bf16* __restrict__ Xv,
    const bf16* __restrict__ Wqt, const bf16* __restrict__ Wkt, const bf16* __restrict__ Wvt,
    bf16* __restrict__ Qb, bf16* __restrict__ Kb, bf16* __restrict__ VtG) {
    __shared__ __align__(16) bf16 As[128 * 64];
    __shared__ __align__(16) bf16 Bs[128 * 64];
    const int z = blockIdx.z;
    const int blk = blockIdx.x;
    const bf16* A; const bf16* Bt; bf16* C; int N; float scale; int m0, n0;
    if (z == 0) { A = Xq; Bt = Wqt; C = Qb; N = 1024;
                  scale = 0.125f * 1.44269504088896340736f;
                  m0 = (blk >> 3) * 128; n0 = (blk & 7) * 128; }
    else if (z == 1) { A = Xk; Bt = Wkt; C = Kb; N = 1024; scale = 1.0f;
                  m0 = (blk >> 3) * 128; n0 = (blk & 7) * 128; }
    else { A = Wvt; Bt = Xv; C = VtG; N = 8192; scale = 1.0f;
                  m0 = (blk >> 6) * 128; n0 = (blk & 63) * 128; }
    gemm_body<bf16>(A, Bt, C, N, 1024, scale, m0, n0, As, Bs);
}

// Output projection: out[8192][1024] fp32 = Cb * Wot^T
__global__ __launch_bounds__(256) void gemm_out(const bf16* __restrict__ A,
                                                const bf16* __restrict__ Bt,
                                                float* __restrict__ C) {
    __shared__ __align__(16) bf16 As[128 * 64];
    __shared__ __align__(16) bf16 Bs[128 * 64];
    gemm_body<float>(A, Bt, C, 1024, 1024, 1.0f, blockIdx.y * 128, blockIdx.x * 128,
                     As, Bs);
}

// ---------------------------------------------------------------------------
// Flash attention, S^T formulation, no online max (|s|<=~8 in log2 domain:
// fp32-safe). Q pre-scaled by 0.125*log2e so P = exp2(s) directly.
// Single-buffered staging (34.8 KB LDS -> 4 blocks/CU). Zero-C trick for the
// S^T MFMAs; l accumulated as f32x4 (packed adds), reduced once at the end.
// ---------------------------------------------------------------------------
__global__ __launch_bounds__(256) void attn_fa(const bf16* __restrict__ Q,
                                               const bf16* __restrict__ K,
                                               const bf16* __restrict__ Vt,
                                               bf16* __restrict__ O) {
    __shared__ __align__(16) bf16 Ks[64 * 64];      // swizzled [t][dh]
    __shared__ __align__(16) bf16 Vs[64 * 64];      // swizzled [dh][t]
    __shared__ __align__(16) bf16 Pt[4][32 * 72];   // per-wave P^T [q][t], pad 72

    const int t = threadIdx.x;
    const int lane = t & 63;
    const int w = t >> 6;
    const int l15 = lane & 15;
    const int quad = lane >> 4;
    const int bh = blockIdx.y;
    const int b = bh >> 4, h = bh & 15;
    const int q0 = blockIdx.x * 128;
    const size_t baseQ = (size_t)b * 2048 * 1024 + (size_t)h * 64;

    // staging chunk mapping (xor swizzle, 16B granular)
    const int r0s = t >> 3,          g0s = (t & 7) ^ (r0s & 7);
    const int r1s = (t + 256) >> 3,  g1s = ((t + 256) & 7) ^ (r1s & 7);
    const bf16* gK0 = K + baseQ + (size_t)r0s * 1024 + g0s * 8;
    const bf16* gK1 = K + baseQ + (size_t)r1s * 1024 + g1s * 8;
    const bf16* gV0 = Vt + (size_t)(h * 64 + r0s) * 8192 + (size_t)b * 2048 + g0s * 8;
    const bf16* gV1 = Vt + (size_t)(h * 64 + r1s) * 8192 + (size_t)b * 2048 + g1s * 8;
    bf16* lcK0 = (bf16*)Ks + w * 512;
    bf16* lcK1 = (bf16*)Ks + 2048 + w * 512;
    bf16* lcV0 = (bf16*)Vs + w * 512;
    bf16* lcV1 = (bf16*)Vs + 2048 + w * 512;

    // Q fragments (B-operand): [n=q=mi*16+l15][k=dh=kk*32+quad*8..]
    bf16x8 qf[2][2];
#pragma unroll
    for (int mi = 0; mi < 2; ++mi)
#pragma unroll
        for (int kk = 0; kk < 2; ++kk)
            qf[mi][kk] = *(const bf16x8*)(Q + baseQ +
                (size_t)(q0 + w * 32 + mi * 16 + l15) * 1024 + kk * 32 + quad * 8);

    f32x4 accO[4][2];                 // O^T tiles: [d-tile nd][q-tile mi]
    f32x4 l4[2];                      // vectorized l partials
#pragma unroll
    for (int nd = 0; nd < 4; ++nd)
#pragma unroll
        for (int mi = 0; mi < 2; ++mi) accO[nd][mi] = (f32x4){0.f, 0.f, 0.f, 0.f};
    l4[0] = (f32x4){0.f, 0.f, 0.f, 0.f};
    l4[1] = (f32x4){0.f, 0.f, 0.f, 0.f};
    const f32x4 z4 = {0.f, 0.f, 0.f, 0.f};   // persistent zero C-operand

    auto swz = [&](int r, int g) { return (r * 8 + (g ^ (r & 7))) * 8; };

    for (int t0 = 0; t0 < 2048; t0 += 64) {
        __syncthreads();
        async16(lcK0, gK0 + (size_t)t0 * 1024);
        async16(lcK1, gK1 + (size_t)t0 * 1024);
        async16(lcV0, gV0 + t0);
        async16(lcV1, gV1 + t0);
        __syncthreads();

        // S^T = K_tile * Q^T : accS[nt][mi]; row t = nt*16+quad*4+r, col q = mi*16+l15
        f32x4 accS[4][2];
        {
            bf16x8 kf[4];
#pragma unroll
            for (int nt = 0; nt < 4; ++nt)
                kf[nt] = *(const bf16x8*)&Ks[swz(nt * 16 + l15, quad)];
#pragma unroll
            for (int nt = 0; nt < 4; ++nt)
#pragma unroll
                for (int mi = 0; mi < 2; ++mi)
                    accS[nt][mi] = __builtin_amdgcn_mfma_f32_16x16x32_bf16(
                        kf[nt], qf[mi][0], z4, 0, 0, 0);
#pragma unroll
            for (int nt = 0; nt < 4; ++nt)
                kf[nt] = *(const bf16x8*)&Ks[swz(nt * 16 + l15, 4 + quad)];
#pragma unroll
            for (int nt = 0; nt < 4; ++nt)
#pragma unroll
                for (int mi = 0; mi < 2; ++mi)
                    accS[nt][mi] = __builtin_amdgcn_mfma_f32_16x16x32_bf16(
                        kf[nt], qf[mi][1], accS[nt][mi], 0, 0, 0);
        }

        // P = exp2(s) (log2 domain), vectorized l partials; P^T -> LDS b64
        bf16* Pp = &Pt[w][0];
#pragma unroll
        for (int mi = 0; mi < 2; ++mi) {
#pragma unroll
            for (int nt = 0; nt < 4; ++nt) {
                bf16x4 pk;
#pragma unroll
                for (int r = 0; r < 4; ++r) {
                    float p = __builtin_amdgcn_exp2f(accS[nt][mi][r]);
                    accS[nt][mi][r] = p;
                    pk[r] = (bf16)p;
                }
                l4[mi] += accS[nt][mi];
                *(bf16x4*)&Pp[(mi * 16 + l15) * 72 + nt * 16 + quad * 4] = pk;
            }
        }

        // O^T += V^T * P^T
#pragma unroll
        for (int kk = 0; kk < 2; ++kk) {
            bf16x8 vf[4], pf[2];
#pragma unroll
            for (int nd = 0; nd < 4; ++nd)
                vf[nd] = *(const bf16x8*)&Vs[swz(nd * 16 + l15, kk * 4 + quad)];
#pragma unroll
            for (int mi = 0; mi < 2; ++mi)
                pf[mi] = *(const bf16x8*)&Pp[(mi * 16 + l15) * 72 + kk * 32 + quad * 8];
#pragma unroll
            for (int nd = 0; nd < 4; ++nd)
#pragma unroll
                for (int mi = 0; mi < 2; ++mi)
                    accO[nd][mi] = __builtin_amdgcn_mfma_f32_16x16x32_bf16(
                        vf[nd], pf[mi], accO[nd][mi], 0, 0, 0);
        }
    }

    // final l reduction: horizontal over f32x4, then across quads
    float inv[2];
#pragma unroll
    for (int mi = 0; mi < 2; ++mi) {
        float l = (l4[mi][0] + l4[mi][1]) + (l4[mi][2] + l4[mi][3]);
        l += __shfl_xor(l, 16);
        l += __shfl_xor(l, 32);
        inv[mi] = 1.0f / l;
    }

    // epilogue: ctx[q][h*64+d] = O^T[d][q]/l ; 8B stores
#pragma unroll
    for (int mi = 0; mi < 2; ++mi) {
        size_t rowoff = baseQ + (size_t)(q0 + w * 32 + mi * 16 + l15) * 1024;
#pragma unroll
        for (int nd = 0; nd < 4; ++nd) {
            bf16x4 o;
#pragma unroll
            for (int r = 0; r < 4; ++r) o[r] = (bf16)(accO[nd][mi][r] * inv[mi]);
            *(bf16x4*)&O[rowoff + nd * 16 + quad * 4] = o;
        }
    }
}

// ---------------------------------------------------------------------------
extern "C" void kernel_launch(void* const* d_in, const int* in_sizes, int n_in,
                              void* d_out, int out_size, void* d_ws, size_t ws_size,
                              hipStream_t stream) {
    const float* qin = (const float*)d_in[0];
    const float* kin = (const float*)d_in[1];
    const float* vin = (const float*)d_in[2];
    const float* Wq = (const float*)d_in[3];
    const float* Wk = (const float*)d_in[4];
    const float* Wv = (const float*)d_in[5];
    const float* Wo = (const float*)d_in[6];
    float* out = (float*)d_out;

    char* ws = (char*)d_ws;
    bf16* Xq  = (bf16*)(ws);                       // 16 MB each
    bf16* Xk  = (bf16*)(ws + ((size_t)16 << 20));
    bf16* Xv  = (bf16*)(ws + ((size_t)32 << 20));
    bf16* Qb  = (bf16*)(ws + ((size_t)48 << 20));
    bf16* Kb  = (bf16*)(ws + ((size_t)64 << 20));
    bf16* VtG = (bf16*)(ws + ((size_t)80 << 20));  // [1024][8192] = V^T
    bf16* Cb  = (bf16*)(ws);                       // alias Xq (dead after gemm_qkv)
    bf16* Wqt = (bf16*)(ws + ((size_t)96 << 20));
    bf16* Wkt = Wqt + 1024 * 1024;
    bf16* Wvt = Wkt + 1024 * 1024;
    bf16* Wot = Wvt + 1024 * 1024;

    prep<<<dim3(4096, 1, 4), 256, 0, stream>>>(qin, kin, vin, Xq, Xk, Xv,
                                               Wq, Wk, Wv, Wo, Wqt, Wkt, Wvt, Wot);
    gemm_qkv<<<dim3(512, 1, 3), 256, 0, stream>>>(Xq, Xk, Xv, Wqt, Wkt, Wvt,
                                                  Qb, Kb, VtG);
    attn_fa<<<dim3(16, 64), 256, 0, stream>>>(Qb, Kb, VtG, Cb);
    gemm_out<<<dim3(8, 64), 256, 0, stream>>>(Cb, Wot, out);
}